// Round 12
// baseline (34.689 us; speedup 1.0000x reference)
//
#include <hip/hip_runtime.h>
#include <math.h>

#define NSAMP 524288              // 2^19 samples per channel
#define CHUNK 8                   // samples per thread
#define WGT 256                   // threads per workgroup (4 waves)
#define NWGC 256                  // workgroups per channel
#define TOTWG 512                 // total workgroups (regular launch, 2/CU)
#define HIDDEN 16
#define NTAB 256                  // p(theta) lookup table size

__device__ __forceinline__ float fast_tanh(float x) {
    float e = __expf(2.0f * x);
    return (e - 1.0f) / (e + 1.0f);
}

// (Mo,do) = (Ma,da) ∘ (Mb,db): apply b first, then a
__device__ __forceinline__ void compose5(const float* Ma, const float* da,
                                         const float* Mb, const float* db,
                                         float* Mo, float* dout) {
#pragma unroll
    for (int r = 0; r < 5; ++r) {
#pragma unroll
        for (int c = 0; c < 5; ++c) {
            float acc = 0.0f;
#pragma unroll
            for (int k = 0; k < 5; ++k) acc = fmaf(Ma[r*5+k], Mb[k*5+c], acc);
            Mo[r*5+c] = acc;
        }
        float acc = da[r];
#pragma unroll
        for (int k = 0; k < 5; ++k) acc = fmaf(Ma[r*5+k], db[k], acc);
        dout[r] = acc;
    }
}

// relaxed agent-scope helpers (sc1 load/store; NO cache maintenance)
__device__ __forceinline__ float ld_agent(const float* p) {
    return __hip_atomic_load(p, __ATOMIC_RELAXED, __HIP_MEMORY_SCOPE_AGENT);
}
__device__ __forceinline__ void st_agent(float* p, float v) {
    __hip_atomic_store(p, v, __ATOMIC_RELAXED, __HIP_MEMORY_SCOPE_AGENT);
}
__device__ __forceinline__ unsigned ldu_agent(const unsigned* p) {
    return __hip_atomic_load(p, __ATOMIC_RELAXED, __HIP_MEMORY_SCOPE_AGENT);
}
__device__ __forceinline__ void stu_agent(unsigned* p, unsigned v) {
    __hip_atomic_store(p, v, __ATOMIC_RELAXED, __HIP_MEMORY_SCOPE_AGENT);
}

// in-register inclusive scan across the 64 lanes of a wave (6 shfl steps)
__device__ __forceinline__ void wave_incl_scan(float* M, float* d, int l) {
#pragma unroll
    for (int off = 1; off < 64; off <<= 1) {
        float pM[25], pd[5];
#pragma unroll
        for (int k = 0; k < 25; ++k) pM[k] = __shfl_up(M[k], (unsigned)off);
#pragma unroll
        for (int k = 0; k < 5; ++k)  pd[k] = __shfl_up(d[k], (unsigned)off);
        if (l >= off) {
            float Mn[25], dn[5];
            compose5(M, d, pM, pd, Mn, dn);     // cur ∘ prev
#pragma unroll
            for (int k = 0; k < 25; ++k) M[k] = Mn[k];
#pragma unroll
            for (int k = 0; k < 5; ++k)  d[k] = dn[k];
        }
    }
}

// exclusive prefix of the wave aggregates in LDS: P = W_{w-1} ∘ ... ∘ W_0
__device__ __forceinline__ void wave_prefix(const float wAp[][33], int w,
                                            float* PM, float* Pd) {
#pragma unroll
    for (int k = 0; k < 25; ++k) PM[k] = (k % 6 == 0) ? 1.0f : 0.0f;
#pragma unroll
    for (int k = 0; k < 5; ++k)  Pd[k] = 0.0f;
    for (int j = 0; j < w; ++j) {              // wave-uniform bound (0..3)
        float Wm[25], Wd[5], Mn[25], dn[5];
#pragma unroll
        for (int k = 0; k < 25; ++k) Wm[k] = wAp[j][k];       // LDS broadcast
#pragma unroll
        for (int k = 0; k < 5; ++k)  Wd[k] = wAp[j][25 + k];
        compose5(Wm, Wd, PM, Pd, Mn, dn);
#pragma unroll
        for (int k = 0; k < 25; ++k) PM[k] = Mn[k];
#pragma unroll
        for (int k = 0; k < 5; ++k)  Pd[k] = dn[k];
    }
}

__global__ void __launch_bounds__(WGT, 2) k_fused(
    const float* __restrict__ X,
    const float* __restrict__ rate01,
    const float* __restrict__ phoff01,
    const float* __restrict__ W1,
    const float* __restrict__ b1,
    const float* __restrict__ W2,
    const float* __restrict__ b2,
    const float* __restrict__ amp,
    const float* __restrict__ bias_,
    const float* __restrict__ depth_,
    const float* __restrict__ g1p,
    const float* __restrict__ prevph,
    float* __restrict__ OUT,
    float* __restrict__ RECT,     // transposed: RECT[k*TOTWG + vid], k<30
    unsigned int* __restrict__ FLG)   // zeroed per call by memsetAsync
{
    __shared__ float Tp[NTAB];
    __shared__ float wA[4][33];   // per-wave aggregates (30 used, pad to 33)
    __shared__ float sES[8];      // channel-prefix d-part broadcast

    const int t   = threadIdx.x;
    const int vid = blockIdx.x;
    const int c   = vid >> 8;           // NWGC = 256
    const int wc  = vid & (NWGC - 1);
    const int w   = t >> 6;             // wave id (0..3)
    const int l   = t & 63;             // lane id

    const int gblk = wc * WGT + t;      // block idx within channel
    const long base = (long)c * NSAMP + (long)gblk * CHUNK;

    // hoist X loads: HBM latency overlaps the table build below
    float xv[CHUNK];
    {
        const float4* Xv = (const float4*)(X + base);
        float4 a = Xv[0], b = Xv[1];
        xv[0]=a.x; xv[1]=a.y; xv[2]=a.z; xv[3]=a.w;
        xv[4]=b.x; xv[5]=b.y; xv[6]=b.z; xv[7]=b.w;
    }

    const float two_pi = 6.28318530717958647692f;
    const float rate   = fmaf(rate01[0], 4.9f, 0.1f);
    const float w0rev  = rate / 44100.0f;                    // rev per sample
    const float dscale = depth_[0] * 0.5f;
    const float g1     = g1p[0];

    // ============ Phase 0: build p(theta) table (1 entry/thread) ===========
    {
        float lfo = amp[0] * __cosf((float)t * (two_pi / (float)NTAB));
        float m = b2[0];
#pragma unroll
        for (int jj = 0; jj < HIDDEN; ++jj) {
            float h = fast_tanh(fmaf(lfo, W1[jj], b1[jj]));
            m = fmaf(h, W2[jj], m);
        }
        float dd = fmaf(dscale, 1.0f + m, bias_[0]);
        float td = __tanf(dd);
        Tp[t] = fast_tanh((1.0f - td) / (1.0f + td));
    }
    __syncthreads();

    const float phrev = prevph[0] * (1.0f / two_pi) + (c ? phoff01[0] : 0.0f);

    // ============ Phase A: per-sample coefficient via table lookup =========
    float pv[CHUNK];
#pragma unroll
    for (int k = 0; k < CHUNK; ++k) {
        float ph = fmaf(w0rev, (float)(gblk * CHUNK + k + 1), phrev);
        float u = (ph - floorf(ph)) * (float)NTAB;
        int i0 = ((int)u) & (NTAB - 1);
        float f = u - floorf(u);
        int i1 = (i0 + 1) & (NTAB - 1);
        float t0 = Tp[i0];
        pv[k] = fmaf(f, Tp[i1] - t0, t0);
    }

    // ========== Phase B: per-block transform (M 5x5, d 5) ==================
    float v[6][5];
#pragma unroll
    for (int j = 0; j < 6; ++j)
#pragma unroll
        for (int r = 0; r < 5; ++r) v[j][r] = (j == r) ? 1.0f : 0.0f;

#pragma unroll
    for (int k = 0; k < CHUNK; ++k) {
        float pp = pv[k], xx = xv[k];
#pragma unroll
        for (int j = 0; j < 6; ++j) {
            float xin = (j == 5) ? xx : 0.0f;
            float u0 = fmaf(g1, v[j][4], xin);
            float y0 = fmaf(pp, u0 - v[j][1], v[j][0]);
            float y1 = fmaf(pp, y0 - v[j][2], v[j][1]);
            float y2 = fmaf(pp, y1 - v[j][3], v[j][2]);
            float y3 = fmaf(pp, y2 - v[j][4], v[j][3]);
            v[j][0] = u0; v[j][1] = y0; v[j][2] = y1; v[j][3] = y2; v[j][4] = y3;
        }
    }

    float M[25], d[5];
#pragma unroll
    for (int j = 0; j < 5; ++j)
#pragma unroll
        for (int r = 0; r < 5; ++r) M[r*5+j] = v[j][r];
#pragma unroll
    for (int r = 0; r < 5; ++r) d[r] = v[5][r];

    // ========== intra-wave inclusive scan + cross-wave prefix ==============
    wave_incl_scan(M, d, l);
    if (l == 63) {
#pragma unroll
        for (int k = 0; k < 25; ++k) wA[w][k] = M[k];
#pragma unroll
        for (int k = 0; k < 5; ++k)  wA[w][25 + k] = d[k];
    }
    __syncthreads();
    float PM[25], Pd[5];                // exclusive wave prefix for my wave
    wave_prefix(wA, w, PM, Pd);

    // ===== publish WG total = incl(255) ∘ P3 (thread 255), transposed =====
    if (t == WGT - 1) {
        float Tm[25], Td[5];
        compose5(M, d, PM, Pd, Tm, Td);
#pragma unroll
        for (int k = 0; k < 25; ++k) st_agent(&RECT[k*TOTWG + vid], Tm[k]);
#pragma unroll
        for (int k = 0; k < 5; ++k)  st_agent(&RECT[(25+k)*TOTWG + vid], Td[k]);
    }
    __syncthreads();                    // wave3 drains vmcnt before barrier
    if (t == 0) {
        asm volatile("" ::: "memory");
        stu_agent(&FLG[vid], 1u);
    }

    // ===== flat lookback: every WG scans aggregates 0..wc-1 (id-padded) ====
    // FLG starts all-zero this call (memsetAsync) -> consumers can only see
    // 0 (wait) or this call's 1. No dependence on prior d_ws state.
    float aM[25], ad[5];
    if (t < wc) {
        const unsigned int* fp = &FLG[c * NWGC + t];
        while (ldu_agent(fp) == 0u) { __builtin_amdgcn_s_sleep(1); }
        asm volatile("" ::: "memory");
#pragma unroll
        for (int k = 0; k < 25; ++k)    // coalesced across t
            aM[k] = ld_agent(&RECT[k*TOTWG + c*NWGC + t]);
#pragma unroll
        for (int k = 0; k < 5; ++k)
            ad[k] = ld_agent(&RECT[(25+k)*TOTWG + c*NWGC + t]);
    } else {
#pragma unroll
        for (int k = 0; k < 25; ++k) aM[k] = (k % 6 == 0) ? 1.0f : 0.0f;
#pragma unroll
        for (int k = 0; k < 5; ++k)  ad[k] = 0.0f;
    }

    wave_incl_scan(aM, ad, l);
    if (l == 63) {                      // all threads past the publish barrier
#pragma unroll
        for (int k = 0; k < 25; ++k) wA[w][k] = aM[k];
#pragma unroll
        for (int k = 0; k < 5; ++k)  wA[w][25 + k] = ad[k];
    }
    __syncthreads();
    if (t == WGT - 1) {                 // total = product(0..wc-1); d = sw
        float aPM[25], aPd[5];
        wave_prefix(wA, w, aPM, aPd);
        float Tm[25], Td[5];
        compose5(aM, ad, aPM, aPd, Tm, Td);
#pragma unroll
        for (int r = 0; r < 5; ++r) sES[r] = Td[r];
    }
    __syncthreads();

    float sw[5];
#pragma unroll
    for (int r = 0; r < 5; ++r) sw[r] = sES[r];

    // ====== Phase D: s = E_lane( P_wave( sw ) ), then run recursion ========
    float s1[5];
#pragma unroll
    for (int r = 0; r < 5; ++r) {
        float acc = Pd[r];
#pragma unroll
        for (int j = 0; j < 5; ++j) acc = fmaf(PM[r*5+j], sw[j], acc);
        s1[r] = acc;
    }
    float s0, s1r, s2, s3, s4;
    {
        float s[5];
#pragma unroll
        for (int r = 0; r < 5; ++r) {
            float acc = __shfl_up(d[r], 1u);
#pragma unroll
            for (int j = 0; j < 5; ++j)
                acc = fmaf(__shfl_up(M[r*5+j], 1u), s1[j], acc);
            s[r] = (l == 0) ? s1[r] : acc;
        }
        s0 = s[0]; s1r = s[1]; s2 = s[2]; s3 = s[3]; s4 = s[4];
    }

    {
        float4* Ov = (float4*)(OUT + base);
        float oa[CHUNK];
#pragma unroll
        for (int k = 0; k < CHUNK; ++k) {
            float pp = pv[k], xx = xv[k];
            float u0 = fmaf(g1, s4, xx);
            float y0 = fmaf(pp, u0 - s1r, s0);
            float y1 = fmaf(pp, y0 - s2, s1r);
            float y2 = fmaf(pp, y1 - s3, s2);
            float y3 = fmaf(pp, y2 - s4, s3);
            s0 = u0; s1r = y0; s2 = y1; s3 = y2; s4 = y3;
            oa[k] = 0.5f * (xx + y3);
        }
        float4 o0; o0.x = oa[0]; o0.y = oa[1]; o0.z = oa[2]; o0.w = oa[3];
        float4 o1; o1.x = oa[4]; o1.y = oa[5]; o1.z = oa[6]; o1.w = oa[7];
        Ov[0] = o0; Ov[1] = o1;
    }
}

extern "C" void kernel_launch(void* const* d_in, const int* in_sizes, int n_in,
                              void* d_out, int out_size, void* d_ws, size_t ws_size,
                              hipStream_t stream) {
    const float* x     = (const float*)d_in[0];
    const float* rate  = (const float*)d_in[1];
    const float* phoff = (const float*)d_in[2];
    const float* W1    = (const float*)d_in[3];
    const float* b1    = (const float*)d_in[4];
    const float* W2    = (const float*)d_in[5];
    const float* b2    = (const float*)d_in[6];
    const float* amp   = (const float*)d_in[7];
    const float* bias_ = (const float*)d_in[8];
    const float* depth = (const float*)d_in[9];
    const float* g1    = (const float*)d_in[10];
    const float* pph   = (const float*)d_in[11];
    float* out = (float*)d_out;

    float* RECT = (float*)d_ws;                         // 30*TOTWG floats
    unsigned int* FLG = (unsigned int*)(RECT + 30L * TOTWG);

    // per-call flag zeroing, captured in the graph: every launch has an
    // identical synchronization trajectory (tripwire-safe; round-11 lesson)
    hipMemsetAsync(FLG, 0, TOTWG * sizeof(unsigned int), stream);

    k_fused<<<dim3(TOTWG), dim3(WGT), 0, stream>>>(
        x, rate, phoff, W1, b1, W2, b2, amp, bias_, depth, g1, pph,
        out, RECT, FLG);
}

// Round 14
// 27.984 us; speedup vs baseline: 1.2396x; 1.2396x over previous
//
#include <hip/hip_runtime.h>
#include <math.h>

#define NSAMP 524288              // 2^19 samples per channel
#define CHUNK 8                   // samples per thread
#define WGT 256                   // threads per workgroup (4 waves)
#define NWGC 256                  // workgroups per channel
#define TOTWG 512                 // total workgroups (regular launch, 2/CU)
#define HIDDEN 16
#define NTAB 256                  // p(theta) lookup table size

__device__ __forceinline__ float fast_tanh(float x) {
    float e = __expf(2.0f * x);
    return (e - 1.0f) / (e + 1.0f);
}

// (Mo,do) = (Ma,da) ∘ (Mb,db): apply b first, then a
__device__ __forceinline__ void compose5(const float* Ma, const float* da,
                                         const float* Mb, const float* db,
                                         float* Mo, float* dout) {
#pragma unroll
    for (int r = 0; r < 5; ++r) {
#pragma unroll
        for (int c = 0; c < 5; ++c) {
            float acc = 0.0f;
#pragma unroll
            for (int k = 0; k < 5; ++k) acc = fmaf(Ma[r*5+k], Mb[k*5+c], acc);
            Mo[r*5+c] = acc;
        }
        float acc = da[r];
#pragma unroll
        for (int k = 0; k < 5; ++k) acc = fmaf(Ma[r*5+k], db[k], acc);
        dout[r] = acc;
    }
}

// relaxed agent-scope helpers (sc1 load/store; NO cache maintenance)
__device__ __forceinline__ float ld_agent(const float* p) {
    return __hip_atomic_load(p, __ATOMIC_RELAXED, __HIP_MEMORY_SCOPE_AGENT);
}
__device__ __forceinline__ void st_agent(float* p, float v) {
    __hip_atomic_store(p, v, __ATOMIC_RELAXED, __HIP_MEMORY_SCOPE_AGENT);
}
__device__ __forceinline__ unsigned ldu_agent(const unsigned* p) {
    return __hip_atomic_load(p, __ATOMIC_RELAXED, __HIP_MEMORY_SCOPE_AGENT);
}
__device__ __forceinline__ void stu_agent(unsigned* p, unsigned v) {
    __hip_atomic_store(p, v, __ATOMIC_RELAXED, __HIP_MEMORY_SCOPE_AGENT);
}

// in-register inclusive scan across the 64 lanes of a wave (6 shfl steps)
__device__ __forceinline__ void wave_incl_scan(float* M, float* d, int l) {
#pragma unroll
    for (int off = 1; off < 64; off <<= 1) {
        float pM[25], pd[5];
#pragma unroll
        for (int k = 0; k < 25; ++k) pM[k] = __shfl_up(M[k], (unsigned)off);
#pragma unroll
        for (int k = 0; k < 5; ++k)  pd[k] = __shfl_up(d[k], (unsigned)off);
        if (l >= off) {
            float Mn[25], dn[5];
            compose5(M, d, pM, pd, Mn, dn);     // cur ∘ prev
#pragma unroll
            for (int k = 0; k < 25; ++k) M[k] = Mn[k];
#pragma unroll
            for (int k = 0; k < 5; ++k)  d[k] = dn[k];
        }
    }
}

// exclusive prefix of the wave aggregates in LDS: P = W_{w-1} ∘ ... ∘ W_0
__device__ __forceinline__ void wave_prefix(const float wAp[][33], int w,
                                            float* PM, float* Pd) {
#pragma unroll
    for (int k = 0; k < 25; ++k) PM[k] = (k % 6 == 0) ? 1.0f : 0.0f;
#pragma unroll
    for (int k = 0; k < 5; ++k)  Pd[k] = 0.0f;
    for (int j = 0; j < w; ++j) {              // wave-uniform bound (0..3)
        float Wm[25], Wd[5], Mn[25], dn[5];
#pragma unroll
        for (int k = 0; k < 25; ++k) Wm[k] = wAp[j][k];       // LDS broadcast
#pragma unroll
        for (int k = 0; k < 5; ++k)  Wd[k] = wAp[j][25 + k];
        compose5(Wm, Wd, PM, Pd, Mn, dn);
#pragma unroll
        for (int k = 0; k < 25; ++k) PM[k] = Mn[k];
#pragma unroll
        for (int k = 0; k < 5; ++k)  Pd[k] = dn[k];
    }
}

__global__ void __launch_bounds__(WGT, 2) k_fused(
    const float* __restrict__ X,
    const float* __restrict__ rate01,
    const float* __restrict__ phoff01,
    const float* __restrict__ W1,
    const float* __restrict__ b1,
    const float* __restrict__ W2,
    const float* __restrict__ b2,
    const float* __restrict__ amp,
    const float* __restrict__ bias_,
    const float* __restrict__ depth_,
    const float* __restrict__ g1p,
    const float* __restrict__ prevph,
    float* __restrict__ OUT,
    float* __restrict__ RECT,     // transposed: RECT[k*TOTWG + vid], k<30
    float* __restrict__ EST,      // transposed: EST[r*TOTWG + vid], r<5
    unsigned int* __restrict__ FLG,    // consume-and-clear: single reader each
    unsigned int* __restrict__ FLG2)
{
    __shared__ float Tp[NTAB];
    __shared__ float wA[4][33];   // per-wave aggregates (30 used, pad to 33)
    __shared__ float sES[8];      // entry-state broadcast

    const int t   = threadIdx.x;
    const int vid = blockIdx.x;
    const int c   = vid >> 8;           // NWGC = 256
    const int wc  = vid & (NWGC - 1);
    const int w   = t >> 6;             // wave id (0..3)
    const int l   = t & 63;             // lane id

    const int gblk = wc * WGT + t;      // block idx within channel
    const long base = (long)c * NSAMP + (long)gblk * CHUNK;

    // hoist X loads: HBM latency overlaps the table build below
    float xv[CHUNK];
    {
        const float4* Xv = (const float4*)(X + base);
        float4 a = Xv[0], b = Xv[1];
        xv[0]=a.x; xv[1]=a.y; xv[2]=a.z; xv[3]=a.w;
        xv[4]=b.x; xv[5]=b.y; xv[6]=b.z; xv[7]=b.w;
    }

    const float two_pi = 6.28318530717958647692f;
    const float rate   = fmaf(rate01[0], 4.9f, 0.1f);
    const float w0rev  = rate / 44100.0f;                    // rev per sample
    const float dscale = depth_[0] * 0.5f;
    const float g1     = g1p[0];

    // ============ Phase 0: build p(theta) table (1 entry/thread) ===========
    {
        float lfo = amp[0] * __cosf((float)t * (two_pi / (float)NTAB));
        float m = b2[0];
#pragma unroll
        for (int jj = 0; jj < HIDDEN; ++jj) {
            float h = fast_tanh(fmaf(lfo, W1[jj], b1[jj]));
            m = fmaf(h, W2[jj], m);
        }
        float dd = fmaf(dscale, 1.0f + m, bias_[0]);
        float td = __tanf(dd);
        Tp[t] = fast_tanh((1.0f - td) / (1.0f + td));
    }
    __syncthreads();

    const float phrev = prevph[0] * (1.0f / two_pi) + (c ? phoff01[0] : 0.0f);

    // ============ Phase A: per-sample coefficient via table lookup =========
    float pv[CHUNK];
#pragma unroll
    for (int k = 0; k < CHUNK; ++k) {
        float ph = fmaf(w0rev, (float)(gblk * CHUNK + k + 1), phrev);
        float u = (ph - floorf(ph)) * (float)NTAB;
        int i0 = ((int)u) & (NTAB - 1);
        float f = u - floorf(u);
        int i1 = (i0 + 1) & (NTAB - 1);
        float t0 = Tp[i0];
        pv[k] = fmaf(f, Tp[i1] - t0, t0);
    }

    // ========== Phase B: per-block transform (M 5x5, d 5) ==================
    float v[6][5];
#pragma unroll
    for (int j = 0; j < 6; ++j)
#pragma unroll
        for (int r = 0; r < 5; ++r) v[j][r] = (j == r) ? 1.0f : 0.0f;

#pragma unroll
    for (int k = 0; k < CHUNK; ++k) {
        float pp = pv[k], xx = xv[k];
#pragma unroll
        for (int j = 0; j < 6; ++j) {
            float xin = (j == 5) ? xx : 0.0f;
            float u0 = fmaf(g1, v[j][4], xin);
            float y0 = fmaf(pp, u0 - v[j][1], v[j][0]);
            float y1 = fmaf(pp, y0 - v[j][2], v[j][1]);
            float y2 = fmaf(pp, y1 - v[j][3], v[j][2]);
            float y3 = fmaf(pp, y2 - v[j][4], v[j][3]);
            v[j][0] = u0; v[j][1] = y0; v[j][2] = y1; v[j][3] = y2; v[j][4] = y3;
        }
    }

    float M[25], d[5];
#pragma unroll
    for (int j = 0; j < 5; ++j)
#pragma unroll
        for (int r = 0; r < 5; ++r) M[r*5+j] = v[j][r];
#pragma unroll
    for (int r = 0; r < 5; ++r) d[r] = v[5][r];

    // ========== intra-wave inclusive scan + cross-wave prefix ==============
    wave_incl_scan(M, d, l);
    if (l == 63) {
#pragma unroll
        for (int k = 0; k < 25; ++k) wA[w][k] = M[k];
#pragma unroll
        for (int k = 0; k < 5; ++k)  wA[w][25 + k] = d[k];
    }
    __syncthreads();
    float PM[25], Pd[5];                // exclusive wave prefix for my wave
    wave_prefix(wA, w, PM, Pd);

    // ===== publish WG total = incl(255) ∘ P3 (thread 255), transposed =====
    if (t == WGT - 1) {
        float Tm[25], Td[5];
        compose5(M, d, PM, Pd, Tm, Td);
#pragma unroll
        for (int k = 0; k < 25; ++k) st_agent(&RECT[k*TOTWG + vid], Tm[k]);
#pragma unroll
        for (int k = 0; k < 5; ++k)  st_agent(&RECT[(25+k)*TOTWG + vid], Td[k]);
    }
    __syncthreads();                    // wave3 drains vmcnt before barrier
    if (t == 0) {
        asm volatile("" ::: "memory");
        stu_agent(&FLG[vid], 1u);       // sole reader: master thread t=wc slot
    }

    // ===== Phase C (master WGs, wc==0): scan 256 channel aggregates ========
    // Flag invariant: FLG/FLG2 are 0 (cleared by previous call's single
    // reader) or 0xAA.. (fresh poison) at call entry -> spin `!= 1` always
    // waits for THIS call's publish. No stale state is ever consumable.
    if (wc == 0) {
        const unsigned int* fp = &FLG[c * NWGC + t];
        while (ldu_agent(fp) != 1u) { __builtin_amdgcn_s_sleep(1); }
        asm volatile("" ::: "memory");
        float aM[25], ad[5];
#pragma unroll
        for (int k = 0; k < 25; ++k)    // coalesced across t
            aM[k] = ld_agent(&RECT[k*TOTWG + c*NWGC + t]);
#pragma unroll
        for (int k = 0; k < 5; ++k)
            ad[k] = ld_agent(&RECT[(25+k)*TOTWG + c*NWGC + t]);
        stu_agent((unsigned int*)&FLG[c * NWGC + t], 0u);   // consume-and-clear

        wave_incl_scan(aM, ad, l);
        if (l == 63) {                  // all threads past the publish barrier
#pragma unroll
            for (int k = 0; k < 25; ++k) wA[w][k] = aM[k];
#pragma unroll
            for (int k = 0; k < 5; ++k)  wA[w][25 + k] = ad[k];
        }
        __syncthreads();
        float aPM[25], aPd[5];
        wave_prefix(wA, w, aPM, aPd);

        // ES[t] = (exclusive prefix of aggregates)(0) = E_lane( aPd )
        float es[5];
#pragma unroll
        for (int r = 0; r < 5; ++r) {
            float acc = __shfl_up(ad[r], 1u);
#pragma unroll
            for (int j = 0; j < 5; ++j)
                acc = fmaf(__shfl_up(aM[r*5+j], 1u), aPd[j], acc);
            es[r] = (l == 0) ? aPd[r] : acc;
        }
#pragma unroll
        for (int r = 0; r < 5; ++r)     // coalesced across t
            st_agent(&EST[r*TOTWG + c*NWGC + t], es[r]);
        __syncthreads();                // drain all ES stores (vmcnt 0)
        asm volatile("" ::: "memory");
        stu_agent(&FLG2[c * NWGC + t], 1u);   // sole reader: WG (c,t)'s t0
    }

    // ===== all WGs: obtain entry state (single spinner = thread 0) =========
    if (t == 0) {
        if (wc != 0) {
            unsigned int* fp = &FLG2[vid];
            while (ldu_agent(fp) != 1u) { __builtin_amdgcn_s_sleep(1); }
            asm volatile("" ::: "memory");
#pragma unroll
            for (int r = 0; r < 5; ++r)
                sES[r] = ld_agent(&EST[r*TOTWG + vid]);
            stu_agent(fp, 0u);          // consume-and-clear (sole reader)
        } else {
#pragma unroll
            for (int r = 0; r < 5; ++r) sES[r] = 0.0f;
        }
    }
    __syncthreads();
    float sw[5];
#pragma unroll
    for (int r = 0; r < 5; ++r) sw[r] = sES[r];

    // ====== Phase D: s = E_lane( P_wave( sw ) ), then run recursion ========
    float s1[5];
#pragma unroll
    for (int r = 0; r < 5; ++r) {
        float acc = Pd[r];
#pragma unroll
        for (int j = 0; j < 5; ++j) acc = fmaf(PM[r*5+j], sw[j], acc);
        s1[r] = acc;
    }
    float s0, s1r, s2, s3, s4;
    {
        float s[5];
#pragma unroll
        for (int r = 0; r < 5; ++r) {
            float acc = __shfl_up(d[r], 1u);
#pragma unroll
            for (int j = 0; j < 5; ++j)
                acc = fmaf(__shfl_up(M[r*5+j], 1u), s1[j], acc);
            s[r] = (l == 0) ? s1[r] : acc;
        }
        s0 = s[0]; s1r = s[1]; s2 = s[2]; s3 = s[3]; s4 = s[4];
    }

    {
        float4* Ov = (float4*)(OUT + base);
        float oa[CHUNK];
#pragma unroll
        for (int k = 0; k < CHUNK; ++k) {
            float pp = pv[k], xx = xv[k];
            float u0 = fmaf(g1, s4, xx);
            float y0 = fmaf(pp, u0 - s1r, s0);
            float y1 = fmaf(pp, y0 - s2, s1r);
            float y2 = fmaf(pp, y1 - s3, s2);
            float y3 = fmaf(pp, y2 - s4, s3);
            s0 = u0; s1r = y0; s2 = y1; s3 = y2; s4 = y3;
            oa[k] = 0.5f * (xx + y3);
        }
        float4 o0; o0.x = oa[0]; o0.y = oa[1]; o0.z = oa[2]; o0.w = oa[3];
        float4 o1; o1.x = oa[4]; o1.y = oa[5]; o1.z = oa[6]; o1.w = oa[7];
        Ov[0] = o0; Ov[1] = o1;
    }
}

extern "C" void kernel_launch(void* const* d_in, const int* in_sizes, int n_in,
                              void* d_out, int out_size, void* d_ws, size_t ws_size,
                              hipStream_t stream) {
    const float* x     = (const float*)d_in[0];
    const float* rate  = (const float*)d_in[1];
    const float* phoff = (const float*)d_in[2];
    const float* W1    = (const float*)d_in[3];
    const float* b1    = (const float*)d_in[4];
    const float* W2    = (const float*)d_in[5];
    const float* b2    = (const float*)d_in[6];
    const float* amp   = (const float*)d_in[7];
    const float* bias_ = (const float*)d_in[8];
    const float* depth = (const float*)d_in[9];
    const float* g1    = (const float*)d_in[10];
    const float* pph   = (const float*)d_in[11];
    float* out = (float*)d_out;

    float* RECT = (float*)d_ws;                         // 30*TOTWG floats
    float* EST  = RECT + 30L * TOTWG;                   // 5*TOTWG floats
    unsigned int* FLG  = (unsigned int*)(EST + 5L * TOTWG);
    unsigned int* FLG2 = FLG + TOTWG;

    // single dispatch; consume-and-clear flags need no per-call init
    k_fused<<<dim3(TOTWG), dim3(WGT), 0, stream>>>(
        x, rate, phoff, W1, b1, W2, b2, amp, bias_, depth, g1, pph,
        out, RECT, EST, FLG, FLG2);
}

// Round 15
// 24.814 us; speedup vs baseline: 1.3980x; 1.1278x over previous
//
#include <hip/hip_runtime.h>
#include <math.h>

#define NSAMP 524288              // 2^19 samples per channel
#define CHUNK 8                   // samples per thread
#define WGT 256                   // threads per workgroup (4 waves)
#define NWGC 256                  // workgroups per channel
#define TOTWG 512                 // total workgroups (regular launch, 2/CU)
#define HIDDEN 16
#define NTAB 256                  // p(theta) lookup table size

typedef float f32x2 __attribute__((ext_vector_type(2)));

__device__ __forceinline__ float fast_tanh(float x) {
    float e = __expf(2.0f * x);
    return (e - 1.0f) / (e + 1.0f);
}

// Augmented-affine record: T[r][j], r<5 rows; j<5 = matrix cols, j=5 = d.
// Stored as 15 f32x2 pairs: row r = pairs {r*3, r*3+1, r*3+2}.
// O = A ∘ B (apply B first, then A). 75 packed mul-adds (v_pk_fma_f32).
__device__ __forceinline__ void compose6(const f32x2* A, const f32x2* B,
                                         f32x2* O) {
#pragma unroll
    for (int r = 0; r < 5; ++r) {
        f32x2 acc0 = {0.0f, 0.0f};
        f32x2 acc1 = {0.0f, 0.0f};
        f32x2 acc2 = {0.0f, A[r*3 + 2][1]};   // carry da[r] into out d
#pragma unroll
        for (int k = 0; k < 5; ++k) {
            float a = A[r*3 + k/2][k%2];
            f32x2 as = {a, a};
            acc0 += as * B[k*3 + 0];
            acc1 += as * B[k*3 + 1];
            acc2 += as * B[k*3 + 2];
        }
        O[r*3 + 0] = acc0; O[r*3 + 1] = acc1; O[r*3 + 2] = acc2;
    }
}

__device__ __forceinline__ void set_identity6(f32x2* T) {
#pragma unroll
    for (int q = 0; q < 15; ++q) { f32x2 z = {0.0f, 0.0f}; T[q] = z; }
#pragma unroll
    for (int r = 0; r < 5; ++r) T[(7*r)/2][(7*r)%2] = 1.0f;  // elem r*6+r
}

// relaxed agent-scope helpers (sc1 load/store; NO cache maintenance)
__device__ __forceinline__ float ld_agent(const float* p) {
    return __hip_atomic_load(p, __ATOMIC_RELAXED, __HIP_MEMORY_SCOPE_AGENT);
}
__device__ __forceinline__ void st_agent(float* p, float v) {
    __hip_atomic_store(p, v, __ATOMIC_RELAXED, __HIP_MEMORY_SCOPE_AGENT);
}
__device__ __forceinline__ unsigned ldu_agent(const unsigned* p) {
    return __hip_atomic_load(p, __ATOMIC_RELAXED, __HIP_MEMORY_SCOPE_AGENT);
}
__device__ __forceinline__ void stu_agent(unsigned* p, unsigned v) {
    __hip_atomic_store(p, v, __ATOMIC_RELAXED, __HIP_MEMORY_SCOPE_AGENT);
}

// in-register inclusive scan across the 64 lanes of a wave (6 shfl steps)
__device__ __forceinline__ void wave_incl_scan6(f32x2* T, int l) {
#pragma unroll
    for (int off = 1; off < 64; off <<= 1) {
        f32x2 p[15];
#pragma unroll
        for (int q = 0; q < 15; ++q) {
            p[q][0] = __shfl_up(T[q][0], (unsigned)off);
            p[q][1] = __shfl_up(T[q][1], (unsigned)off);
        }
        if (l >= off) {
            f32x2 n[15];
            compose6(T, p, n);                  // cur ∘ prev
#pragma unroll
            for (int q = 0; q < 15; ++q) T[q] = n[q];
        }
    }
}

// exclusive prefix of the wave aggregates in LDS: P = W_{w-1} ∘ ... ∘ W_0
__device__ __forceinline__ void wave_prefix6(const f32x2 wAp[][16], int w,
                                             f32x2* P) {
    set_identity6(P);
    for (int j = 0; j < w; ++j) {              // wave-uniform bound (0..3)
        f32x2 Wm[15], n[15];
#pragma unroll
        for (int q = 0; q < 15; ++q) Wm[q] = wAp[j][q];       // LDS broadcast
        compose6(Wm, P, n);
#pragma unroll
        for (int q = 0; q < 15; ++q) P[q] = n[q];
    }
}

__global__ void __launch_bounds__(WGT, 2) k_fused(
    const float* __restrict__ X,
    const float* __restrict__ rate01,
    const float* __restrict__ phoff01,
    const float* __restrict__ W1,
    const float* __restrict__ b1,
    const float* __restrict__ W2,
    const float* __restrict__ b2,
    const float* __restrict__ amp,
    const float* __restrict__ bias_,
    const float* __restrict__ depth_,
    const float* __restrict__ g1p,
    const float* __restrict__ prevph,
    float* __restrict__ OUT,
    float* __restrict__ RECT,     // transposed: RECT[k*TOTWG + vid], k<30
    float* __restrict__ EST,      // transposed: EST[r*TOTWG + vid], r<5
    unsigned int* __restrict__ FLG,    // consume-and-clear: single reader each
    unsigned int* __restrict__ FLG2)
{
    __shared__ float Tp[NTAB];
    __shared__ f32x2 wA[4][16];   // per-wave aggregates (15 pairs, pad to 16)
    __shared__ float sES[8];      // entry-state broadcast

    const int t   = threadIdx.x;
    const int vid = blockIdx.x;
    const int c   = vid >> 8;           // NWGC = 256
    const int wc  = vid & (NWGC - 1);
    const int w   = t >> 6;             // wave id (0..3)
    const int l   = t & 63;             // lane id

    const int gblk = wc * WGT + t;      // block idx within channel
    const long base = (long)c * NSAMP + (long)gblk * CHUNK;

    // hoist X loads: HBM latency overlaps the table build below
    float xv[CHUNK];
    {
        const float4* Xv = (const float4*)(X + base);
        float4 a = Xv[0], b = Xv[1];
        xv[0]=a.x; xv[1]=a.y; xv[2]=a.z; xv[3]=a.w;
        xv[4]=b.x; xv[5]=b.y; xv[6]=b.z; xv[7]=b.w;
    }

    const float two_pi = 6.28318530717958647692f;
    const float rate   = fmaf(rate01[0], 4.9f, 0.1f);
    const float w0rev  = rate / 44100.0f;                    // rev per sample
    const float dscale = depth_[0] * 0.5f;
    const float g1     = g1p[0];

    // ============ Phase 0: build p(theta) table (1 entry/thread) ===========
    {
        float lfo = amp[0] * __cosf((float)t * (two_pi / (float)NTAB));
        float m = b2[0];
#pragma unroll
        for (int jj = 0; jj < HIDDEN; ++jj) {
            float h = fast_tanh(fmaf(lfo, W1[jj], b1[jj]));
            m = fmaf(h, W2[jj], m);
        }
        float dd = fmaf(dscale, 1.0f + m, bias_[0]);
        float td = __tanf(dd);
        Tp[t] = fast_tanh((1.0f - td) / (1.0f + td));
    }
    __syncthreads();

    const float phrev = prevph[0] * (1.0f / two_pi) + (c ? phoff01[0] : 0.0f);

    // ============ Phase A: per-sample coefficient via table lookup =========
    float pv[CHUNK];
#pragma unroll
    for (int k = 0; k < CHUNK; ++k) {
        float ph = fmaf(w0rev, (float)(gblk * CHUNK + k + 1), phrev);
        float u = (ph - floorf(ph)) * (float)NTAB;
        int i0 = ((int)u) & (NTAB - 1);
        float f = u - floorf(u);
        int i1 = (i0 + 1) & (NTAB - 1);
        float t0 = Tp[i0];
        pv[k] = fmaf(f, Tp[i1] - t0, t0);
    }

    // ========== Phase B: per-block transform, packed basis pairs ===========
    // pair p tracks basis vectors j=2p, 2p+1; pair 2 = [col4 | d] directly.
    f32x2 v2[3][5];
#pragma unroll
    for (int p = 0; p < 3; ++p)
#pragma unroll
        for (int r = 0; r < 5; ++r) {
            f32x2 e; e[0] = (2*p == r) ? 1.0f : 0.0f;
            e[1] = (2*p + 1 == r) ? 1.0f : 0.0f;
            v2[p][r] = e;
        }

    {
        const f32x2 g1s = {g1, g1};
#pragma unroll
        for (int k = 0; k < CHUNK; ++k) {
            const f32x2 pp2 = {pv[k], pv[k]};
#pragma unroll
            for (int p = 0; p < 3; ++p) {
                f32x2 xin2 = {0.0f, (p == 2) ? xv[k] : 0.0f};
                f32x2 u0 = g1s * v2[p][4] + xin2;
                f32x2 y0 = pp2 * (u0 - v2[p][1]) + v2[p][0];
                f32x2 y1 = pp2 * (y0 - v2[p][2]) + v2[p][1];
                f32x2 y2 = pp2 * (y1 - v2[p][3]) + v2[p][2];
                f32x2 y3 = pp2 * (y2 - v2[p][4]) + v2[p][3];
                v2[p][0] = u0; v2[p][1] = y0; v2[p][2] = y1;
                v2[p][3] = y2; v2[p][4] = y3;
            }
        }
    }

    // record T: row r = [M(r,0..4) | d(r)] -> pairs come straight from v2
    f32x2 T[15];
#pragma unroll
    for (int r = 0; r < 5; ++r) {
        T[r*3 + 0] = v2[0][r];
        T[r*3 + 1] = v2[1][r];
        T[r*3 + 2] = v2[2][r];
    }

    // ========== intra-wave inclusive scan + cross-wave prefix ==============
    wave_incl_scan6(T, l);
    if (l == 63) {
#pragma unroll
        for (int q = 0; q < 15; ++q) wA[w][q] = T[q];
    }
    __syncthreads();
    f32x2 P[15];                        // exclusive wave prefix for my wave
    wave_prefix6(wA, w, P);

    // ===== publish WG total = incl(255) ∘ P3 (thread 255), transposed =====
    if (t == WGT - 1) {
        f32x2 Tot[15];
        compose6(T, P, Tot);
#pragma unroll
        for (int k = 0; k < 30; ++k)
            st_agent(&RECT[k*TOTWG + vid], Tot[k/2][k%2]);
    }
    __syncthreads();                    // wave3 drains vmcnt before barrier
    if (t == 0) {
        asm volatile("" ::: "memory");
        stu_agent(&FLG[vid], 1u);       // sole reader: master thread t=wc slot
    }

    // ===== Phase C (master WGs, wc==0): scan 256 channel aggregates ========
    // Flag invariant: FLG/FLG2 are 0 (cleared by previous call's single
    // reader) or 0xAA.. (fresh poison) at call entry -> spin `!= 1` always
    // waits for THIS call's publish. No stale state is ever consumable.
    if (wc == 0) {
        const unsigned int* fp = &FLG[c * NWGC + t];
        while (ldu_agent(fp) != 1u) { __builtin_amdgcn_s_sleep(1); }
        asm volatile("" ::: "memory");
        f32x2 aT[15];
#pragma unroll
        for (int k = 0; k < 30; ++k)    // coalesced across t
            aT[k/2][k%2] = ld_agent(&RECT[k*TOTWG + c*NWGC + t]);
        stu_agent((unsigned int*)&FLG[c * NWGC + t], 0u);   // consume-and-clear

        wave_incl_scan6(aT, l);
        if (l == 63) {                  // all threads past the publish barrier
#pragma unroll
            for (int q = 0; q < 15; ++q) wA[w][q] = aT[q];
        }
        __syncthreads();
        f32x2 aP[15];
        wave_prefix6(wA, w, aP);
        float aPd[5];
#pragma unroll
        for (int j = 0; j < 5; ++j) aPd[j] = aP[(j*6+5)/2][(j*6+5)%2];

        // ES[t] = exclusive prefix of aggregates applied to zero state
        float es[5];
#pragma unroll
        for (int r = 0; r < 5; ++r) {
            float acc = __shfl_up(aT[r*3 + 2][1], 1u);      // ad[r]
#pragma unroll
            for (int j = 0; j < 5; ++j)
                acc = fmaf(__shfl_up(aT[r*3 + j/2][j%2], 1u), aPd[j], acc);
            es[r] = (l == 0) ? aPd[r] : acc;
        }
#pragma unroll
        for (int r = 0; r < 5; ++r)     // coalesced across t
            st_agent(&EST[r*TOTWG + c*NWGC + t], es[r]);
        __syncthreads();                // drain all ES stores (vmcnt 0)
        asm volatile("" ::: "memory");
        stu_agent(&FLG2[c * NWGC + t], 1u);   // sole reader: WG (c,t)'s t0
    }

    // ===== all WGs: obtain entry state (single spinner = thread 0) =========
    if (t == 0) {
        if (wc != 0) {
            unsigned int* fp = &FLG2[vid];
            while (ldu_agent(fp) != 1u) { __builtin_amdgcn_s_sleep(1); }
            asm volatile("" ::: "memory");
#pragma unroll
            for (int r = 0; r < 5; ++r)
                sES[r] = ld_agent(&EST[r*TOTWG + vid]);
            stu_agent(fp, 0u);          // consume-and-clear (sole reader)
        } else {
#pragma unroll
            for (int r = 0; r < 5; ++r) sES[r] = 0.0f;
        }
    }
    __syncthreads();
    float sw[5];
#pragma unroll
    for (int r = 0; r < 5; ++r) sw[r] = sES[r];

    // ====== Phase D: s = E_lane( P_wave( sw ) ), then run recursion ========
    float s1[5];
#pragma unroll
    for (int r = 0; r < 5; ++r) {
        float acc = P[r*3 + 2][1];                          // Pd[r]
#pragma unroll
        for (int j = 0; j < 5; ++j)
            acc = fmaf(P[r*3 + j/2][j%2], sw[j], acc);
        s1[r] = acc;
    }
    float s0, s1r, s2, s3, s4;
    {
        float s[5];
#pragma unroll
        for (int r = 0; r < 5; ++r) {
            float acc = __shfl_up(T[r*3 + 2][1], 1u);       // d[r]
#pragma unroll
            for (int j = 0; j < 5; ++j)
                acc = fmaf(__shfl_up(T[r*3 + j/2][j%2], 1u), s1[j], acc);
            s[r] = (l == 0) ? s1[r] : acc;
        }
        s0 = s[0]; s1r = s[1]; s2 = s[2]; s3 = s[3]; s4 = s[4];
    }

    {
        float4* Ov = (float4*)(OUT + base);
        float oa[CHUNK];
#pragma unroll
        for (int k = 0; k < CHUNK; ++k) {
            float pp = pv[k], xx = xv[k];
            float u0 = fmaf(g1, s4, xx);
            float y0 = fmaf(pp, u0 - s1r, s0);
            float y1 = fmaf(pp, y0 - s2, s1r);
            float y2 = fmaf(pp, y1 - s3, s2);
            float y3 = fmaf(pp, y2 - s4, s3);
            s0 = u0; s1r = y0; s2 = y1; s3 = y2; s4 = y3;
            oa[k] = 0.5f * (xx + y3);
        }
        float4 o0; o0.x = oa[0]; o0.y = oa[1]; o0.z = oa[2]; o0.w = oa[3];
        float4 o1; o1.x = oa[4]; o1.y = oa[5]; o1.z = oa[6]; o1.w = oa[7];
        Ov[0] = o0; Ov[1] = o1;
    }
}

extern "C" void kernel_launch(void* const* d_in, const int* in_sizes, int n_in,
                              void* d_out, int out_size, void* d_ws, size_t ws_size,
                              hipStream_t stream) {
    const float* x     = (const float*)d_in[0];
    const float* rate  = (const float*)d_in[1];
    const float* phoff = (const float*)d_in[2];
    const float* W1    = (const float*)d_in[3];
    const float* b1    = (const float*)d_in[4];
    const float* W2    = (const float*)d_in[5];
    const float* b2    = (const float*)d_in[6];
    const float* amp   = (const float*)d_in[7];
    const float* bias_ = (const float*)d_in[8];
    const float* depth = (const float*)d_in[9];
    const float* g1    = (const float*)d_in[10];
    const float* pph   = (const float*)d_in[11];
    float* out = (float*)d_out;

    float* RECT = (float*)d_ws;                         // 30*TOTWG floats
    float* EST  = RECT + 30L * TOTWG;                   // 5*TOTWG floats
    unsigned int* FLG  = (unsigned int*)(EST + 5L * TOTWG);
    unsigned int* FLG2 = FLG + TOTWG;

    // single dispatch; consume-and-clear flags need no per-call init
    k_fused<<<dim3(TOTWG), dim3(WGT), 0, stream>>>(
        x, rate, phoff, W1, b1, W2, b2, amp, bias_, depth, g1, pph,
        out, RECT, EST, FLG, FLG2);
}

// Round 16
// 22.289 us; speedup vs baseline: 1.5564x; 1.1133x over previous
//
#include <hip/hip_runtime.h>
#include <math.h>

#define NSAMP 524288              // 2^19 samples per channel
#define CHUNK 16                  // samples per thread
#define WGT 256                   // threads per workgroup (4 waves)
#define NWGC 128                  // workgroups per channel
#define TOTWG 256                 // total workgroups (1 per CU)
#define HIDDEN 16
#define NTAB 256                  // p(theta) lookup table size

typedef float f32x2 __attribute__((ext_vector_type(2)));

__device__ __forceinline__ float fast_tanh(float x) {
    float e = __expf(2.0f * x);
    return (e - 1.0f) / (e + 1.0f);
}

// Augmented-affine record: T[r][j], r<5 rows; j<5 = matrix cols, j=5 = d.
// Stored as 15 f32x2 pairs: row r = pairs {r*3, r*3+1, r*3+2}.
// O = A ∘ B (apply B first, then A). 75 packed mul-adds (v_pk_fma_f32).
__device__ __forceinline__ void compose6(const f32x2* A, const f32x2* B,
                                         f32x2* O) {
#pragma unroll
    for (int r = 0; r < 5; ++r) {
        f32x2 acc0 = {0.0f, 0.0f};
        f32x2 acc1 = {0.0f, 0.0f};
        f32x2 acc2 = {0.0f, A[r*3 + 2][1]};   // carry da[r] into out d
#pragma unroll
        for (int k = 0; k < 5; ++k) {
            float a = A[r*3 + k/2][k%2];
            f32x2 as = {a, a};
            acc0 += as * B[k*3 + 0];
            acc1 += as * B[k*3 + 1];
            acc2 += as * B[k*3 + 2];
        }
        O[r*3 + 0] = acc0; O[r*3 + 1] = acc1; O[r*3 + 2] = acc2;
    }
}

__device__ __forceinline__ void set_identity6(f32x2* T) {
#pragma unroll
    for (int q = 0; q < 15; ++q) { f32x2 z = {0.0f, 0.0f}; T[q] = z; }
#pragma unroll
    for (int r = 0; r < 5; ++r) T[(7*r)/2][(7*r)%2] = 1.0f;  // elem r*6+r
}

// relaxed agent-scope helpers (sc1 load/store; NO cache maintenance)
__device__ __forceinline__ float ld_agent(const float* p) {
    return __hip_atomic_load(p, __ATOMIC_RELAXED, __HIP_MEMORY_SCOPE_AGENT);
}
__device__ __forceinline__ void st_agent(float* p, float v) {
    __hip_atomic_store(p, v, __ATOMIC_RELAXED, __HIP_MEMORY_SCOPE_AGENT);
}
__device__ __forceinline__ unsigned ldu_agent(const unsigned* p) {
    return __hip_atomic_load(p, __ATOMIC_RELAXED, __HIP_MEMORY_SCOPE_AGENT);
}
__device__ __forceinline__ void stu_agent(unsigned* p, unsigned v) {
    __hip_atomic_store(p, v, __ATOMIC_RELAXED, __HIP_MEMORY_SCOPE_AGENT);
}

// in-register inclusive scan across the 64 lanes of a wave (6 shfl steps)
__device__ __forceinline__ void wave_incl_scan6(f32x2* T, int l) {
#pragma unroll
    for (int off = 1; off < 64; off <<= 1) {
        f32x2 p[15];
#pragma unroll
        for (int q = 0; q < 15; ++q) {
            p[q][0] = __shfl_up(T[q][0], (unsigned)off);
            p[q][1] = __shfl_up(T[q][1], (unsigned)off);
        }
        if (l >= off) {
            f32x2 n[15];
            compose6(T, p, n);                  // cur ∘ prev
#pragma unroll
            for (int q = 0; q < 15; ++q) T[q] = n[q];
        }
    }
}

// exclusive prefix of the wave aggregates in LDS: P = W_{w-1} ∘ ... ∘ W_0
__device__ __forceinline__ void wave_prefix6(const f32x2 wAp[][16], int w,
                                             f32x2* P) {
    set_identity6(P);
    for (int j = 0; j < w; ++j) {              // wave-uniform bound (0..3)
        f32x2 Wm[15], n[15];
#pragma unroll
        for (int q = 0; q < 15; ++q) Wm[q] = wAp[j][q];       // LDS broadcast
        compose6(Wm, P, n);
#pragma unroll
        for (int q = 0; q < 15; ++q) P[q] = n[q];
    }
}

__global__ void __launch_bounds__(WGT, 1) k_fused(
    const float* __restrict__ X,
    const float* __restrict__ rate01,
    const float* __restrict__ phoff01,
    const float* __restrict__ W1,
    const float* __restrict__ b1,
    const float* __restrict__ W2,
    const float* __restrict__ b2,
    const float* __restrict__ amp,
    const float* __restrict__ bias_,
    const float* __restrict__ depth_,
    const float* __restrict__ g1p,
    const float* __restrict__ prevph,
    float* __restrict__ OUT,
    float* __restrict__ RECT,     // transposed: RECT[k*TOTWG + vid], k<30
    float* __restrict__ EST,      // transposed: EST[r*TOTWG + vid], r<5
    unsigned int* __restrict__ FLG,    // consume-and-clear: single reader each
    unsigned int* __restrict__ FLG2)
{
    __shared__ float Tp[NTAB];
    __shared__ f32x2 wA[4][16];   // per-wave aggregates (15 pairs, pad to 16)
    __shared__ float sES[8];      // entry-state broadcast

    const int t   = threadIdx.x;
    const int vid = blockIdx.x;
    const int c   = vid >> 7;           // NWGC = 128
    const int wc  = vid & (NWGC - 1);
    const int w   = t >> 6;             // wave id (0..3)
    const int l   = t & 63;             // lane id

    const int gblk = wc * WGT + t;      // block idx within channel
    const long base = (long)c * NSAMP + (long)gblk * CHUNK;

    // hoist X loads: HBM latency overlaps the table build below
    float xv[CHUNK];
    {
        const float4* Xv = (const float4*)(X + base);
#pragma unroll
        for (int q = 0; q < CHUNK / 4; ++q) {
            float4 a = Xv[q];
            xv[q*4+0]=a.x; xv[q*4+1]=a.y; xv[q*4+2]=a.z; xv[q*4+3]=a.w;
        }
    }

    const float two_pi = 6.28318530717958647692f;
    const float rate   = fmaf(rate01[0], 4.9f, 0.1f);
    const float w0rev  = rate / 44100.0f;                    // rev per sample
    const float dscale = depth_[0] * 0.5f;
    const float g1     = g1p[0];

    // ============ Phase 0: build p(theta) table (1 entry/thread) ===========
    {
        float lfo = amp[0] * __cosf((float)t * (two_pi / (float)NTAB));
        float m = b2[0];
#pragma unroll
        for (int jj = 0; jj < HIDDEN; ++jj) {
            float h = fast_tanh(fmaf(lfo, W1[jj], b1[jj]));
            m = fmaf(h, W2[jj], m);
        }
        float dd = fmaf(dscale, 1.0f + m, bias_[0]);
        float td = __tanf(dd);
        Tp[t] = fast_tanh((1.0f - td) / (1.0f + td));
    }
    __syncthreads();

    const float phrev = prevph[0] * (1.0f / two_pi) + (c ? phoff01[0] : 0.0f);

    // ============ Phase A: per-sample coefficient via table lookup =========
    float pv[CHUNK];
#pragma unroll
    for (int k = 0; k < CHUNK; ++k) {
        float ph = fmaf(w0rev, (float)(gblk * CHUNK + k + 1), phrev);
        float u = (ph - floorf(ph)) * (float)NTAB;
        int i0 = ((int)u) & (NTAB - 1);
        float f = u - floorf(u);
        int i1 = (i0 + 1) & (NTAB - 1);
        float t0 = Tp[i0];
        pv[k] = fmaf(f, Tp[i1] - t0, t0);
    }

    // ========== Phase B: per-block transform, packed basis pairs ===========
    // pair p tracks basis vectors j=2p, 2p+1; pair 2 = [col4 | d] directly.
    f32x2 v2[3][5];
#pragma unroll
    for (int p = 0; p < 3; ++p)
#pragma unroll
        for (int r = 0; r < 5; ++r) {
            f32x2 e; e[0] = (2*p == r) ? 1.0f : 0.0f;
            e[1] = (2*p + 1 == r) ? 1.0f : 0.0f;
            v2[p][r] = e;
        }

    {
        const f32x2 g1s = {g1, g1};
#pragma unroll
        for (int k = 0; k < CHUNK; ++k) {
            const f32x2 pp2 = {pv[k], pv[k]};
#pragma unroll
            for (int p = 0; p < 3; ++p) {
                f32x2 xin2 = {0.0f, (p == 2) ? xv[k] : 0.0f};
                f32x2 u0 = g1s * v2[p][4] + xin2;
                f32x2 y0 = pp2 * (u0 - v2[p][1]) + v2[p][0];
                f32x2 y1 = pp2 * (y0 - v2[p][2]) + v2[p][1];
                f32x2 y2 = pp2 * (y1 - v2[p][3]) + v2[p][2];
                f32x2 y3 = pp2 * (y2 - v2[p][4]) + v2[p][3];
                v2[p][0] = u0; v2[p][1] = y0; v2[p][2] = y1;
                v2[p][3] = y2; v2[p][4] = y3;
            }
        }
    }

    // record T: row r = [M(r,0..4) | d(r)] -> pairs come straight from v2
    f32x2 T[15];
#pragma unroll
    for (int r = 0; r < 5; ++r) {
        T[r*3 + 0] = v2[0][r];
        T[r*3 + 1] = v2[1][r];
        T[r*3 + 2] = v2[2][r];
    }

    // ========== intra-wave inclusive scan + cross-wave prefix ==============
    wave_incl_scan6(T, l);
    if (l == 63) {
#pragma unroll
        for (int q = 0; q < 15; ++q) wA[w][q] = T[q];
    }
    __syncthreads();
    f32x2 P[15];                        // exclusive wave prefix for my wave
    wave_prefix6(wA, w, P);

    // ===== publish WG total = incl(255) ∘ P3 (thread 255), transposed =====
    if (t == WGT - 1) {
        f32x2 Tot[15];
        compose6(T, P, Tot);
#pragma unroll
        for (int k = 0; k < 30; ++k)
            st_agent(&RECT[k*TOTWG + vid], Tot[k/2][k%2]);
    }
    __syncthreads();                    // wave3 drains vmcnt before barrier
    if (t == 0) {
        asm volatile("" ::: "memory");
        stu_agent(&FLG[vid], 1u);       // sole reader: master thread t=wc slot
    }

    // ===== Phase C (master WGs, wc==0): scan NWGC channel aggregates ========
    // Flag invariant: FLG/FLG2 are 0 (cleared by previous call's single
    // reader) or 0xAA.. (fresh poison) at call entry -> spin `!= 1` always
    // waits for THIS call's publish. No stale state is ever consumable.
    if (wc == 0) {
        f32x2 aT[15];
        if (t < NWGC) {
            const unsigned int* fp = &FLG[c * NWGC + t];
            while (ldu_agent(fp) != 1u) { __builtin_amdgcn_s_sleep(1); }
            asm volatile("" ::: "memory");
#pragma unroll
            for (int k = 0; k < 30; ++k)    // coalesced across t
                aT[k/2][k%2] = ld_agent(&RECT[k*TOTWG + c*NWGC + t]);
            stu_agent((unsigned int*)&FLG[c * NWGC + t], 0u); // consume+clear
        } else {
            set_identity6(aT);              // pad lanes 128..255
        }

        wave_incl_scan6(aT, l);
        if (l == 63) {                  // all threads past the publish barrier
#pragma unroll
            for (int q = 0; q < 15; ++q) wA[w][q] = aT[q];
        }
        __syncthreads();
        f32x2 aP[15];
        wave_prefix6(wA, w, aP);
        float aPd[5];
#pragma unroll
        for (int j = 0; j < 5; ++j) aPd[j] = aP[(j*6+5)/2][(j*6+5)%2];

        // ES[t] = exclusive prefix of aggregates applied to zero state
        float es[5];
#pragma unroll
        for (int r = 0; r < 5; ++r) {
            float acc = __shfl_up(aT[r*3 + 2][1], 1u);      // ad[r]
#pragma unroll
            for (int j = 0; j < 5; ++j)
                acc = fmaf(__shfl_up(aT[r*3 + j/2][j%2], 1u), aPd[j], acc);
            es[r] = (l == 0) ? aPd[r] : acc;
        }
        if (t < NWGC) {
#pragma unroll
            for (int r = 0; r < 5; ++r)     // coalesced across t
                st_agent(&EST[r*TOTWG + c*NWGC + t], es[r]);
        }
        __syncthreads();                // drain all ES stores (vmcnt 0)
        asm volatile("" ::: "memory");
        if (t < NWGC)
            stu_agent(&FLG2[c * NWGC + t], 1u);   // sole reader: WG (c,t)'s t0
    }

    // ===== all WGs: obtain entry state (single spinner = thread 0) =========
    if (t == 0) {
        if (wc != 0) {
            unsigned int* fp = &FLG2[vid];
            while (ldu_agent(fp) != 1u) { __builtin_amdgcn_s_sleep(1); }
            asm volatile("" ::: "memory");
#pragma unroll
            for (int r = 0; r < 5; ++r)
                sES[r] = ld_agent(&EST[r*TOTWG + vid]);
            stu_agent(fp, 0u);          // consume-and-clear (sole reader)
        } else {
#pragma unroll
            for (int r = 0; r < 5; ++r) sES[r] = 0.0f;
        }
    }
    __syncthreads();
    float sw[5];
#pragma unroll
    for (int r = 0; r < 5; ++r) sw[r] = sES[r];

    // ====== Phase D: s = E_lane( P_wave( sw ) ), then run recursion ========
    float s1[5];
#pragma unroll
    for (int r = 0; r < 5; ++r) {
        float acc = P[r*3 + 2][1];                          // Pd[r]
#pragma unroll
        for (int j = 0; j < 5; ++j)
            acc = fmaf(P[r*3 + j/2][j%2], sw[j], acc);
        s1[r] = acc;
    }
    float s0, s1r, s2, s3, s4;
    {
        float s[5];
#pragma unroll
        for (int r = 0; r < 5; ++r) {
            float acc = __shfl_up(T[r*3 + 2][1], 1u);       // d[r]
#pragma unroll
            for (int j = 0; j < 5; ++j)
                acc = fmaf(__shfl_up(T[r*3 + j/2][j%2], 1u), s1[j], acc);
            s[r] = (l == 0) ? s1[r] : acc;
        }
        s0 = s[0]; s1r = s[1]; s2 = s[2]; s3 = s[3]; s4 = s[4];
    }

    {
        float4* Ov = (float4*)(OUT + base);
#pragma unroll
        for (int q = 0; q < CHUNK / 4; ++q) {
            float oa[4];
#pragma unroll
            for (int ii = 0; ii < 4; ++ii) {
                float pp = pv[q*4 + ii], xx = xv[q*4 + ii];
                float u0 = fmaf(g1, s4, xx);
                float y0 = fmaf(pp, u0 - s1r, s0);
                float y1 = fmaf(pp, y0 - s2, s1r);
                float y2 = fmaf(pp, y1 - s3, s2);
                float y3 = fmaf(pp, y2 - s4, s3);
                s0 = u0; s1r = y0; s2 = y1; s3 = y2; s4 = y3;
                oa[ii] = 0.5f * (xx + y3);
            }
            float4 o; o.x = oa[0]; o.y = oa[1]; o.z = oa[2]; o.w = oa[3];
            Ov[q] = o;
        }
    }
}

extern "C" void kernel_launch(void* const* d_in, const int* in_sizes, int n_in,
                              void* d_out, int out_size, void* d_ws, size_t ws_size,
                              hipStream_t stream) {
    const float* x     = (const float*)d_in[0];
    const float* rate  = (const float*)d_in[1];
    const float* phoff = (const float*)d_in[2];
    const float* W1    = (const float*)d_in[3];
    const float* b1    = (const float*)d_in[4];
    const float* W2    = (const float*)d_in[5];
    const float* b2    = (const float*)d_in[6];
    const float* amp   = (const float*)d_in[7];
    const float* bias_ = (const float*)d_in[8];
    const float* depth = (const float*)d_in[9];
    const float* g1    = (const float*)d_in[10];
    const float* pph   = (const float*)d_in[11];
    float* out = (float*)d_out;

    float* RECT = (float*)d_ws;                         // 30*TOTWG floats
    float* EST  = RECT + 30L * TOTWG;                   // 5*TOTWG floats
    unsigned int* FLG  = (unsigned int*)(EST + 5L * TOTWG);
    unsigned int* FLG2 = FLG + TOTWG;

    // single dispatch; consume-and-clear flags need no per-call init
    k_fused<<<dim3(TOTWG), dim3(WGT), 0, stream>>>(
        x, rate, phoff, W1, b1, W2, b2, amp, bias_, depth, g1, pph,
        out, RECT, EST, FLG, FLG2);
}

// Round 17
// 21.736 us; speedup vs baseline: 1.5959x; 1.0254x over previous
//
#include <hip/hip_runtime.h>
#include <math.h>

#define NSAMP 524288              // 2^19 samples per channel
#define CHUNK 16                  // samples per thread
#define WGT 256                   // threads per workgroup (4 waves)
#define NWGC 128                  // workgroups per channel
#define TOTWG 256                 // total workgroups (1 per CU)
#define HIDDEN 16
#define NTAB 256                  // p(theta) lookup table size

typedef float f32x2 __attribute__((ext_vector_type(2)));

__device__ __forceinline__ float fast_tanh(float x) {
    float e = __expf(2.0f * x);
    return (e - 1.0f) / (e + 1.0f);
}

// Augmented-affine record: T[r][j], r<5 rows; j<5 = matrix cols, j=5 = d.
// Stored as 15 f32x2 pairs: row r = pairs {r*3, r*3+1, r*3+2}.
// O = A ∘ B (apply B first, then A). 75 packed mul-adds (v_pk_fma_f32).
__device__ __forceinline__ void compose6(const f32x2* A, const f32x2* B,
                                         f32x2* O) {
#pragma unroll
    for (int r = 0; r < 5; ++r) {
        f32x2 acc0 = {0.0f, 0.0f};
        f32x2 acc1 = {0.0f, 0.0f};
        f32x2 acc2 = {0.0f, A[r*3 + 2][1]};   // carry da[r] into out d
#pragma unroll
        for (int k = 0; k < 5; ++k) {
            float a = A[r*3 + k/2][k%2];
            f32x2 as = {a, a};
            acc0 += as * B[k*3 + 0];
            acc1 += as * B[k*3 + 1];
            acc2 += as * B[k*3 + 2];
        }
        O[r*3 + 0] = acc0; O[r*3 + 1] = acc1; O[r*3 + 2] = acc2;
    }
}

__device__ __forceinline__ void set_identity6(f32x2* T) {
#pragma unroll
    for (int q = 0; q < 15; ++q) { f32x2 z = {0.0f, 0.0f}; T[q] = z; }
#pragma unroll
    for (int r = 0; r < 5; ++r) T[(7*r)/2][(7*r)%2] = 1.0f;  // elem r*6+r
}

// relaxed agent-scope helpers (sc1 load/store; NO cache maintenance)
__device__ __forceinline__ float ld_agent(const float* p) {
    return __hip_atomic_load(p, __ATOMIC_RELAXED, __HIP_MEMORY_SCOPE_AGENT);
}
__device__ __forceinline__ void st_agent(float* p, float v) {
    __hip_atomic_store(p, v, __ATOMIC_RELAXED, __HIP_MEMORY_SCOPE_AGENT);
}
__device__ __forceinline__ unsigned ldu_agent(const unsigned* p) {
    return __hip_atomic_load(p, __ATOMIC_RELAXED, __HIP_MEMORY_SCOPE_AGENT);
}
__device__ __forceinline__ void stu_agent(unsigned* p, unsigned v) {
    __hip_atomic_store(p, v, __ATOMIC_RELAXED, __HIP_MEMORY_SCOPE_AGENT);
}

// in-register inclusive scan across the 64 lanes of a wave (6 shfl steps)
__device__ __forceinline__ void wave_incl_scan6(f32x2* T, int l) {
#pragma unroll
    for (int off = 1; off < 64; off <<= 1) {
        f32x2 p[15];
#pragma unroll
        for (int q = 0; q < 15; ++q) {
            p[q][0] = __shfl_up(T[q][0], (unsigned)off);
            p[q][1] = __shfl_up(T[q][1], (unsigned)off);
        }
        if (l >= off) {
            f32x2 n[15];
            compose6(T, p, n);                  // cur ∘ prev
#pragma unroll
            for (int q = 0; q < 15; ++q) T[q] = n[q];
        }
    }
}

// exclusive prefix of the wave aggregates in LDS: P = W_{w-1} ∘ ... ∘ W_0
// (w==0 -> identity; w>0 starts from W0, saving the identity compose)
__device__ __forceinline__ void wave_prefix6(const f32x2 wAp[][16], int w,
                                             f32x2* P) {
    if (w == 0) { set_identity6(P); return; }
#pragma unroll
    for (int q = 0; q < 15; ++q) P[q] = wAp[0][q];            // P = W0
    for (int j = 1; j < w; ++j) {              // wave-uniform bound (1..3)
        f32x2 Wm[15], n[15];
#pragma unroll
        for (int q = 0; q < 15; ++q) Wm[q] = wAp[j][q];       // LDS broadcast
        compose6(Wm, P, n);
#pragma unroll
        for (int q = 0; q < 15; ++q) P[q] = n[q];
    }
}

__global__ void __launch_bounds__(WGT, 1) k_fused(
    const float* __restrict__ X,
    const float* __restrict__ rate01,
    const float* __restrict__ phoff01,
    const float* __restrict__ W1,
    const float* __restrict__ b1,
    const float* __restrict__ W2,
    const float* __restrict__ b2,
    const float* __restrict__ amp,
    const float* __restrict__ bias_,
    const float* __restrict__ depth_,
    const float* __restrict__ g1p,
    const float* __restrict__ prevph,
    float* __restrict__ OUT,
    float* __restrict__ RECT,     // transposed: RECT[k*TOTWG + vid], k<30
    float* __restrict__ EST,      // transposed: EST[r*TOTWG + vid], r<5
    unsigned int* __restrict__ FLG,    // consume-and-clear: single reader each
    unsigned int* __restrict__ FLG2)
{
    __shared__ float Tp[NTAB];
    __shared__ f32x2 wA[4][16];   // per-wave aggregates (15 pairs, pad to 16)
    __shared__ float sES[8];      // entry-state broadcast

    const int t   = threadIdx.x;
    const int vid = blockIdx.x;
    const int c   = vid >> 7;           // NWGC = 128
    const int wc  = vid & (NWGC - 1);
    const int w   = t >> 6;             // wave id (0..3)
    const int l   = t & 63;             // lane id

    const int gblk = wc * WGT + t;      // block idx within channel
    const long base = (long)c * NSAMP + (long)gblk * CHUNK;

    // hoist X loads: HBM latency overlaps the table build below
    float xv[CHUNK];
    {
        const float4* Xv = (const float4*)(X + base);
#pragma unroll
        for (int q = 0; q < CHUNK / 4; ++q) {
            float4 a = Xv[q];
            xv[q*4+0]=a.x; xv[q*4+1]=a.y; xv[q*4+2]=a.z; xv[q*4+3]=a.w;
        }
    }

    const float two_pi = 6.28318530717958647692f;
    const float rate   = fmaf(rate01[0], 4.9f, 0.1f);
    const float w0rev  = rate / 44100.0f;                    // rev per sample
    const float dscale = depth_[0] * 0.5f;
    const float g1     = g1p[0];

    // ============ Phase 0: build p(theta) table (1 entry/thread) ===========
    {
        float lfo = amp[0] * __cosf((float)t * (two_pi / (float)NTAB));
        float m = b2[0];
#pragma unroll
        for (int jj = 0; jj < HIDDEN; ++jj) {
            float h = fast_tanh(fmaf(lfo, W1[jj], b1[jj]));
            m = fmaf(h, W2[jj], m);
        }
        float dd = fmaf(dscale, 1.0f + m, bias_[0]);
        float td = __tanf(dd);
        Tp[t] = fast_tanh((1.0f - td) / (1.0f + td));
    }
    __syncthreads();

    const float phrev = prevph[0] * (1.0f / two_pi) + (c ? phoff01[0] : 0.0f);

    // ============ Phase A: per-sample coefficient via table lookup =========
    float pv[CHUNK];
#pragma unroll
    for (int k = 0; k < CHUNK; ++k) {
        float ph = fmaf(w0rev, (float)(gblk * CHUNK + k + 1), phrev);
        float u = (ph - floorf(ph)) * (float)NTAB;
        int i0 = ((int)u) & (NTAB - 1);
        float f = u - floorf(u);
        int i1 = (i0 + 1) & (NTAB - 1);
        float t0 = Tp[i0];
        pv[k] = fmaf(f, Tp[i1] - t0, t0);
    }

    // ========== Phase B: per-block transform, packed basis pairs ===========
    // pair p tracks basis vectors j=2p, 2p+1; pair 2 = [col4 | d] directly.
    f32x2 v2[3][5];
#pragma unroll
    for (int p = 0; p < 3; ++p)
#pragma unroll
        for (int r = 0; r < 5; ++r) {
            f32x2 e; e[0] = (2*p == r) ? 1.0f : 0.0f;
            e[1] = (2*p + 1 == r) ? 1.0f : 0.0f;
            v2[p][r] = e;
        }

    {
        const f32x2 g1s = {g1, g1};
#pragma unroll
        for (int k = 0; k < CHUNK; ++k) {
            const f32x2 pp2 = {pv[k], pv[k]};
#pragma unroll
            for (int p = 0; p < 3; ++p) {
                f32x2 xin2 = {0.0f, (p == 2) ? xv[k] : 0.0f};
                f32x2 u0 = g1s * v2[p][4] + xin2;
                f32x2 y0 = pp2 * (u0 - v2[p][1]) + v2[p][0];
                f32x2 y1 = pp2 * (y0 - v2[p][2]) + v2[p][1];
                f32x2 y2 = pp2 * (y1 - v2[p][3]) + v2[p][2];
                f32x2 y3 = pp2 * (y2 - v2[p][4]) + v2[p][3];
                v2[p][0] = u0; v2[p][1] = y0; v2[p][2] = y1;
                v2[p][3] = y2; v2[p][4] = y3;
            }
        }
    }

    // record T: row r = [M(r,0..4) | d(r)] -> pairs come straight from v2
    f32x2 T[15];
#pragma unroll
    for (int r = 0; r < 5; ++r) {
        T[r*3 + 0] = v2[0][r];
        T[r*3 + 1] = v2[1][r];
        T[r*3 + 2] = v2[2][r];
    }

    // ========== intra-wave inclusive scan + cross-wave prefix ==============
    wave_incl_scan6(T, l);
    if (l == 63) {
#pragma unroll
        for (int q = 0; q < 15; ++q) wA[w][q] = T[q];
    }
    __syncthreads();
    f32x2 P[15];                        // exclusive wave prefix for my wave
    wave_prefix6(wA, w, P);

    // ===== publish WG total = incl(255) ∘ P3 (thread 255), transposed =====
    if (t == WGT - 1) {
        f32x2 Tot[15];
        compose6(T, P, Tot);
#pragma unroll
        for (int k = 0; k < 30; ++k)
            st_agent(&RECT[k*TOTWG + vid], Tot[k/2][k%2]);
    }
    __syncthreads();                    // wave3 drains vmcnt before barrier
    if (t == 0) {
        asm volatile("" ::: "memory");
        stu_agent(&FLG[vid], 1u);       // sole reader: master thread t=wc slot
    }

    // ===== Phase C (master WGs, wc==0): scan NWGC channel aggregates ========
    // Flag invariant: FLG/FLG2 are 0 (cleared by previous call's single
    // reader) or 0xAA.. (fresh poison) at call entry -> spin `!= 1` always
    // waits for THIS call's publish. No stale state is ever consumable.
    if (wc == 0) {
        f32x2 aT[15];
        if (t < NWGC) {
            const unsigned int* fp = &FLG[c * NWGC + t];
            while (ldu_agent(fp) != 1u) { __builtin_amdgcn_s_sleep(1); }
            asm volatile("" ::: "memory");
#pragma unroll
            for (int k = 0; k < 30; ++k)    // coalesced across t
                aT[k/2][k%2] = ld_agent(&RECT[k*TOTWG + c*NWGC + t]);
            stu_agent((unsigned int*)&FLG[c * NWGC + t], 0u); // consume+clear
        } else {
            set_identity6(aT);              // pad lanes 128..255
        }

        wave_incl_scan6(aT, l);
        if (l == 63) {                  // all threads past the publish barrier
#pragma unroll
            for (int q = 0; q < 15; ++q) wA[w][q] = aT[q];
        }
        __syncthreads();
        f32x2 aP[15];
        wave_prefix6(wA, w, aP);
        float aPd[5];
#pragma unroll
        for (int j = 0; j < 5; ++j) aPd[j] = aP[(j*6+5)/2][(j*6+5)%2];

        // ES[t] = exclusive prefix of aggregates applied to zero state
        float es[5];
#pragma unroll
        for (int r = 0; r < 5; ++r) {
            float acc = __shfl_up(aT[r*3 + 2][1], 1u);      // ad[r]
#pragma unroll
            for (int j = 0; j < 5; ++j)
                acc = fmaf(__shfl_up(aT[r*3 + j/2][j%2], 1u), aPd[j], acc);
            es[r] = (l == 0) ? aPd[r] : acc;
        }
        if (t < NWGC) {
#pragma unroll
            for (int r = 0; r < 5; ++r)     // coalesced across t
                st_agent(&EST[r*TOTWG + c*NWGC + t], es[r]);
        }
        __syncthreads();                // drain all ES stores (vmcnt 0)
        asm volatile("" ::: "memory");
        if (t < NWGC)
            stu_agent(&FLG2[c * NWGC + t], 1u);   // sole reader: WG (c,t)'s t0
    }

    // ===== all WGs: obtain entry state (single spinner = thread 0) =========
    if (t == 0) {
        if (wc != 0) {
            unsigned int* fp = &FLG2[vid];
            while (ldu_agent(fp) != 1u) { }     // tight poll: L3 load is the backoff
            asm volatile("" ::: "memory");
#pragma unroll
            for (int r = 0; r < 5; ++r)
                sES[r] = ld_agent(&EST[r*TOTWG + vid]);
            stu_agent(fp, 0u);          // consume-and-clear (sole reader)
        } else {
#pragma unroll
            for (int r = 0; r < 5; ++r) sES[r] = 0.0f;
        }
    }
    __syncthreads();
    float sw[5];
#pragma unroll
    for (int r = 0; r < 5; ++r) sw[r] = sES[r];

    // ====== Phase D: s = E_lane( P_wave( sw ) ), then run recursion ========
    float s1[5];
    if (w == 0) {                       // wave-uniform: P == identity
#pragma unroll
        for (int r = 0; r < 5; ++r) s1[r] = sw[r];
    } else {
#pragma unroll
        for (int r = 0; r < 5; ++r) {
            float acc = P[r*3 + 2][1];                      // Pd[r]
#pragma unroll
            for (int j = 0; j < 5; ++j)
                acc = fmaf(P[r*3 + j/2][j%2], sw[j], acc);
            s1[r] = acc;
        }
    }
    float s0, s1r, s2, s3, s4;
    {
        float s[5];
#pragma unroll
        for (int r = 0; r < 5; ++r) {
            float acc = __shfl_up(T[r*3 + 2][1], 1u);       // d[r]
#pragma unroll
            for (int j = 0; j < 5; ++j)
                acc = fmaf(__shfl_up(T[r*3 + j/2][j%2], 1u), s1[j], acc);
            s[r] = (l == 0) ? s1[r] : acc;
        }
        s0 = s[0]; s1r = s[1]; s2 = s[2]; s3 = s[3]; s4 = s[4];
    }

    {
        float4* Ov = (float4*)(OUT + base);
#pragma unroll
        for (int q = 0; q < CHUNK / 4; ++q) {
            float oa[4];
#pragma unroll
            for (int ii = 0; ii < 4; ++ii) {
                float pp = pv[q*4 + ii], xx = xv[q*4 + ii];
                float u0 = fmaf(g1, s4, xx);
                float y0 = fmaf(pp, u0 - s1r, s0);
                float y1 = fmaf(pp, y0 - s2, s1r);
                float y2 = fmaf(pp, y1 - s3, s2);
                float y3 = fmaf(pp, y2 - s4, s3);
                s0 = u0; s1r = y0; s2 = y1; s3 = y2; s4 = y3;
                oa[ii] = 0.5f * (xx + y3);
            }
            float4 o; o.x = oa[0]; o.y = oa[1]; o.z = oa[2]; o.w = oa[3];
            Ov[q] = o;
        }
    }
}

extern "C" void kernel_launch(void* const* d_in, const int* in_sizes, int n_in,
                              void* d_out, int out_size, void* d_ws, size_t ws_size,
                              hipStream_t stream) {
    const float* x     = (const float*)d_in[0];
    const float* rate  = (const float*)d_in[1];
    const float* phoff = (const float*)d_in[2];
    const float* W1    = (const float*)d_in[3];
    const float* b1    = (const float*)d_in[4];
    const float* W2    = (const float*)d_in[5];
    const float* b2    = (const float*)d_in[6];
    const float* amp   = (const float*)d_in[7];
    const float* bias_ = (const float*)d_in[8];
    const float* depth = (const float*)d_in[9];
    const float* g1    = (const float*)d_in[10];
    const float* pph   = (const float*)d_in[11];
    float* out = (float*)d_out;

    float* RECT = (float*)d_ws;                         // 30*TOTWG floats
    float* EST  = RECT + 30L * TOTWG;                   // 5*TOTWG floats
    unsigned int* FLG  = (unsigned int*)(EST + 5L * TOTWG);
    unsigned int* FLG2 = FLG + TOTWG;

    // single dispatch; consume-and-clear flags need no per-call init
    k_fused<<<dim3(TOTWG), dim3(WGT), 0, stream>>>(
        x, rate, phoff, W1, b1, W2, b2, amp, bias_, depth, g1, pph,
        out, RECT, EST, FLG, FLG2);
}

// Round 18
// 19.612 us; speedup vs baseline: 1.7688x; 1.1083x over previous
//
#include <hip/hip_runtime.h>
#include <math.h>

#define NSAMP 524288              // 2^19 samples per channel
#define CHUNK 16                  // samples per thread
#define WGT 256                   // threads per workgroup (4 waves)
#define NWGC 128                  // workgroups per channel
#define TOTWG 256                 // total workgroups (1 per CU)
#define HIDDEN 16
#define NTAB 256                  // p(theta) lookup table size

typedef float f32x2 __attribute__((ext_vector_type(2)));

__device__ __forceinline__ float fast_tanh(float x) {
    float e = __expf(2.0f * x);
    return (e - 1.0f) / (e + 1.0f);
}

// Augmented-affine record: T[r][j], r<5 rows; j<5 = matrix cols, j=5 = d.
// Stored as 15 f32x2 pairs: row r = pairs {r*3, r*3+1, r*3+2}.
// O = A ∘ B (apply B first, then A). 75 packed mul-adds (v_pk_fma_f32).
__device__ __forceinline__ void compose6(const f32x2* A, const f32x2* B,
                                         f32x2* O) {
#pragma unroll
    for (int r = 0; r < 5; ++r) {
        f32x2 acc0 = {0.0f, 0.0f};
        f32x2 acc1 = {0.0f, 0.0f};
        f32x2 acc2 = {0.0f, A[r*3 + 2][1]};   // carry da[r] into out d
#pragma unroll
        for (int k = 0; k < 5; ++k) {
            float a = A[r*3 + k/2][k%2];
            f32x2 as = {a, a};
            acc0 += as * B[k*3 + 0];
            acc1 += as * B[k*3 + 1];
            acc2 += as * B[k*3 + 2];
        }
        O[r*3 + 0] = acc0; O[r*3 + 1] = acc1; O[r*3 + 2] = acc2;
    }
}

__device__ __forceinline__ void set_identity6(f32x2* T) {
#pragma unroll
    for (int q = 0; q < 15; ++q) { f32x2 z = {0.0f, 0.0f}; T[q] = z; }
#pragma unroll
    for (int r = 0; r < 5; ++r) T[(7*r)/2][(7*r)%2] = 1.0f;  // elem r*6+r
}

// relaxed agent-scope helpers (sc1 load/store; NO cache maintenance)
__device__ __forceinline__ float ld_agent(const float* p) {
    return __hip_atomic_load(p, __ATOMIC_RELAXED, __HIP_MEMORY_SCOPE_AGENT);
}
__device__ __forceinline__ void st_agent(float* p, float v) {
    __hip_atomic_store(p, v, __ATOMIC_RELAXED, __HIP_MEMORY_SCOPE_AGENT);
}
__device__ __forceinline__ unsigned ldu_agent(const unsigned* p) {
    return __hip_atomic_load(p, __ATOMIC_RELAXED, __HIP_MEMORY_SCOPE_AGENT);
}
__device__ __forceinline__ void stu_agent(unsigned* p, unsigned v) {
    __hip_atomic_store(p, v, __ATOMIC_RELAXED, __HIP_MEMORY_SCOPE_AGENT);
}

// in-register inclusive scan across the 64 lanes of a wave (6 shfl steps)
__device__ __forceinline__ void wave_incl_scan6(f32x2* T, int l) {
#pragma unroll
    for (int off = 1; off < 64; off <<= 1) {
        f32x2 p[15];
#pragma unroll
        for (int q = 0; q < 15; ++q) {
            p[q][0] = __shfl_up(T[q][0], (unsigned)off);
            p[q][1] = __shfl_up(T[q][1], (unsigned)off);
        }
        if (l >= off) {
            f32x2 n[15];
            compose6(T, p, n);                  // cur ∘ prev
#pragma unroll
            for (int q = 0; q < 15; ++q) T[q] = n[q];
        }
    }
}

// exclusive prefix of the wave aggregates in LDS: P = W_{w-1} ∘ ... ∘ W_0
// (w==0 -> identity; w>0 starts from W0, saving the identity compose)
__device__ __forceinline__ void wave_prefix6(const f32x2 wAp[][16], int w,
                                             f32x2* P) {
    if (w == 0) { set_identity6(P); return; }
#pragma unroll
    for (int q = 0; q < 15; ++q) P[q] = wAp[0][q];            // P = W0
    for (int j = 1; j < w; ++j) {              // wave-uniform bound (1..3)
        f32x2 Wm[15], n[15];
#pragma unroll
        for (int q = 0; q < 15; ++q) Wm[q] = wAp[j][q];       // LDS broadcast
        compose6(Wm, P, n);
#pragma unroll
        for (int q = 0; q < 15; ++q) P[q] = n[q];
    }
}

__global__ void __launch_bounds__(WGT, 1) k_fused(
    const float* __restrict__ X,
    const float* __restrict__ rate01,
    const float* __restrict__ phoff01,
    const float* __restrict__ W1,
    const float* __restrict__ b1,
    const float* __restrict__ W2,
    const float* __restrict__ b2,
    const float* __restrict__ amp,
    const float* __restrict__ bias_,
    const float* __restrict__ depth_,
    const float* __restrict__ g1p,
    const float* __restrict__ prevph,
    float* __restrict__ OUT,
    float* __restrict__ RECT,     // transposed: RECT[k*TOTWG + vid], k<30
    unsigned int* __restrict__ FLGM)   // [reader][writer] flag matrix,
                                       // single writer + single reader each
{
    __shared__ float Tp[NTAB];
    __shared__ f32x2 wA[4][16];   // per-wave aggregates (15 pairs, pad to 16)
    __shared__ float sES[8];      // entry-state broadcast

    const int t   = threadIdx.x;
    const int vid = blockIdx.x;
    const int c   = vid >> 7;           // NWGC = 128
    const int wc  = vid & (NWGC - 1);
    const int w   = t >> 6;             // wave id (0..3)
    const int l   = t & 63;             // lane id

    const int gblk = wc * WGT + t;      // block idx within channel
    const long base = (long)c * NSAMP + (long)gblk * CHUNK;

    // hoist X loads: HBM latency overlaps the table build below
    float xv[CHUNK];
    {
        const float4* Xv = (const float4*)(X + base);
#pragma unroll
        for (int q = 0; q < CHUNK / 4; ++q) {
            float4 a = Xv[q];
            xv[q*4+0]=a.x; xv[q*4+1]=a.y; xv[q*4+2]=a.z; xv[q*4+3]=a.w;
        }
    }

    const float two_pi = 6.28318530717958647692f;
    const float rate   = fmaf(rate01[0], 4.9f, 0.1f);
    const float w0rev  = rate / 44100.0f;                    // rev per sample
    const float dscale = depth_[0] * 0.5f;
    const float g1     = g1p[0];

    // ============ Phase 0: build p(theta) table (1 entry/thread) ===========
    {
        float lfo = amp[0] * __cosf((float)t * (two_pi / (float)NTAB));
        float m = b2[0];
#pragma unroll
        for (int jj = 0; jj < HIDDEN; ++jj) {
            float h = fast_tanh(fmaf(lfo, W1[jj], b1[jj]));
            m = fmaf(h, W2[jj], m);
        }
        float dd = fmaf(dscale, 1.0f + m, bias_[0]);
        float td = __tanf(dd);
        Tp[t] = fast_tanh((1.0f - td) / (1.0f + td));
    }
    __syncthreads();

    const float phrev = prevph[0] * (1.0f / two_pi) + (c ? phoff01[0] : 0.0f);

    // ============ Phase A: per-sample coefficient via table lookup =========
    float pv[CHUNK];
#pragma unroll
    for (int k = 0; k < CHUNK; ++k) {
        float ph = fmaf(w0rev, (float)(gblk * CHUNK + k + 1), phrev);
        float u = (ph - floorf(ph)) * (float)NTAB;
        int i0 = ((int)u) & (NTAB - 1);
        float f = u - floorf(u);
        int i1 = (i0 + 1) & (NTAB - 1);
        float t0 = Tp[i0];
        pv[k] = fmaf(f, Tp[i1] - t0, t0);
    }

    // ========== Phase B: per-block transform, packed basis pairs ===========
    // pair p tracks basis vectors j=2p, 2p+1; pair 2 = [col4 | d] directly.
    f32x2 v2[3][5];
#pragma unroll
    for (int p = 0; p < 3; ++p)
#pragma unroll
        for (int r = 0; r < 5; ++r) {
            f32x2 e; e[0] = (2*p == r) ? 1.0f : 0.0f;
            e[1] = (2*p + 1 == r) ? 1.0f : 0.0f;
            v2[p][r] = e;
        }

    {
        const f32x2 g1s = {g1, g1};
#pragma unroll
        for (int k = 0; k < CHUNK; ++k) {
            const f32x2 pp2 = {pv[k], pv[k]};
#pragma unroll
            for (int p = 0; p < 3; ++p) {
                f32x2 xin2 = {0.0f, (p == 2) ? xv[k] : 0.0f};
                f32x2 u0 = g1s * v2[p][4] + xin2;
                f32x2 y0 = pp2 * (u0 - v2[p][1]) + v2[p][0];
                f32x2 y1 = pp2 * (y0 - v2[p][2]) + v2[p][1];
                f32x2 y2 = pp2 * (y1 - v2[p][3]) + v2[p][2];
                f32x2 y3 = pp2 * (y2 - v2[p][4]) + v2[p][3];
                v2[p][0] = u0; v2[p][1] = y0; v2[p][2] = y1;
                v2[p][3] = y2; v2[p][4] = y3;
            }
        }
    }

    // record T: row r = [M(r,0..4) | d(r)] -> pairs come straight from v2
    f32x2 T[15];
#pragma unroll
    for (int r = 0; r < 5; ++r) {
        T[r*3 + 0] = v2[0][r];
        T[r*3 + 1] = v2[1][r];
        T[r*3 + 2] = v2[2][r];
    }

    // ========== intra-wave inclusive scan + cross-wave prefix ==============
    wave_incl_scan6(T, l);
    if (l == 63) {
#pragma unroll
        for (int q = 0; q < 15; ++q) wA[w][q] = T[q];
    }
    __syncthreads();
    f32x2 P[15];                        // exclusive wave prefix for my wave
    wave_prefix6(wA, w, P);

    // ===== publish WG total = incl(255) ∘ P3 (thread 255), transposed =====
    if (t == WGT - 1) {
        f32x2 Tot[15];
        compose6(T, P, Tot);
#pragma unroll
        for (int k = 0; k < 30; ++k)
            st_agent(&RECT[k*TOTWG + vid], Tot[k/2][k%2]);
    }
    __syncthreads();                    // wave3 drains vmcnt before barrier
    // notify every reader WG of this channel: thread t handles reader t.
    // Each flag has ONE writer (this WG) and ONE reader (WG (c,t)'s lane wc,
    // which consume-and-clears) -> flags are 0/poison at every call entry.
    if (t < NWGC) {
        asm volatile("" ::: "memory");
        stu_agent(&FLGM[(c * NWGC + t) * NWGC + wc], 1u);
    }

    // ===== flat lookback: scan aggregates 0..wc-1 (identity-padded) ========
    f32x2 aT[15];
    if (t < wc) {                       // wc < 128 -> only waves 0,1 non-id
        unsigned int* fp = &FLGM[(c * NWGC + wc) * NWGC + t];
        while (ldu_agent(fp) != 1u) { __builtin_amdgcn_s_sleep(1); }
        asm volatile("" ::: "memory");
#pragma unroll
        for (int k = 0; k < 30; ++k)    // coalesced across t
            aT[k/2][k%2] = ld_agent(&RECT[k*TOTWG + c*NWGC + t]);
        stu_agent(fp, 0u);              // consume-and-clear (sole reader)
    } else {
        set_identity6(aT);
    }

    if (w < 2) {                        // lanes 128.. are always identity
        wave_incl_scan6(aT, l);
        if (l == 63) {
#pragma unroll
            for (int q = 0; q < 15; ++q) wA[w][q] = aT[q];
        }
    }
    __syncthreads();
    if (t == 0) {                       // Tot = W1 ∘ W0 = product(0..wc-1)
        f32x2 W0[15], W1v[15], Tot[15];
#pragma unroll
        for (int q = 0; q < 15; ++q) { W0[q] = wA[0][q]; W1v[q] = wA[1][q]; }
        compose6(W1v, W0, Tot);
#pragma unroll
        for (int r = 0; r < 5; ++r) sES[r] = Tot[r*3 + 2][1];  // d-part
    }
    __syncthreads();

    float sw[5];
#pragma unroll
    for (int r = 0; r < 5; ++r) sw[r] = sES[r];

    // ====== Phase D: s = E_lane( P_wave( sw ) ), then run recursion ========
    float s1[5];
    if (w == 0) {                       // wave-uniform: P == identity
#pragma unroll
        for (int r = 0; r < 5; ++r) s1[r] = sw[r];
    } else {
#pragma unroll
        for (int r = 0; r < 5; ++r) {
            float acc = P[r*3 + 2][1];                      // Pd[r]
#pragma unroll
            for (int j = 0; j < 5; ++j)
                acc = fmaf(P[r*3 + j/2][j%2], sw[j], acc);
            s1[r] = acc;
        }
    }
    float s0, s1r, s2, s3, s4;
    {
        float s[5];
#pragma unroll
        for (int r = 0; r < 5; ++r) {
            float acc = __shfl_up(T[r*3 + 2][1], 1u);       // d[r]
#pragma unroll
            for (int j = 0; j < 5; ++j)
                acc = fmaf(__shfl_up(T[r*3 + j/2][j%2], 1u), s1[j], acc);
            s[r] = (l == 0) ? s1[r] : acc;
        }
        s0 = s[0]; s1r = s[1]; s2 = s[2]; s3 = s[3]; s4 = s[4];
    }

    {
        float4* Ov = (float4*)(OUT + base);
#pragma unroll
        for (int q = 0; q < CHUNK / 4; ++q) {
            float oa[4];
#pragma unroll
            for (int ii = 0; ii < 4; ++ii) {
                float pp = pv[q*4 + ii], xx = xv[q*4 + ii];
                float u0 = fmaf(g1, s4, xx);
                float y0 = fmaf(pp, u0 - s1r, s0);
                float y1 = fmaf(pp, y0 - s2, s1r);
                float y2 = fmaf(pp, y1 - s3, s2);
                float y3 = fmaf(pp, y2 - s4, s3);
                s0 = u0; s1r = y0; s2 = y1; s3 = y2; s4 = y3;
                oa[ii] = 0.5f * (xx + y3);
            }
            float4 o; o.x = oa[0]; o.y = oa[1]; o.z = oa[2]; o.w = oa[3];
            Ov[q] = o;
        }
    }
}

extern "C" void kernel_launch(void* const* d_in, const int* in_sizes, int n_in,
                              void* d_out, int out_size, void* d_ws, size_t ws_size,
                              hipStream_t stream) {
    const float* x     = (const float*)d_in[0];
    const float* rate  = (const float*)d_in[1];
    const float* phoff = (const float*)d_in[2];
    const float* W1    = (const float*)d_in[3];
    const float* b1    = (const float*)d_in[4];
    const float* W2    = (const float*)d_in[5];
    const float* b2    = (const float*)d_in[6];
    const float* amp   = (const float*)d_in[7];
    const float* bias_ = (const float*)d_in[8];
    const float* depth = (const float*)d_in[9];
    const float* g1    = (const float*)d_in[10];
    const float* pph   = (const float*)d_in[11];
    float* out = (float*)d_out;

    float* RECT = (float*)d_ws;                         // 30*TOTWG floats
    unsigned int* FLGM = (unsigned int*)(RECT + 30L * TOTWG);
    // FLGM: 2 channels * NWGC readers * NWGC writers = 32768 u32 (128 KB)

    // single dispatch; consume-and-clear flag matrix needs no per-call init
    k_fused<<<dim3(TOTWG), dim3(WGT), 0, stream>>>(
        x, rate, phoff, W1, b1, W2, b2, amp, bias_, depth, g1, pph,
        out, RECT, FLGM);
}